// Round 9
// baseline (40.734 us; speedup 1.0000x reference)
//
#include <hip/hip_runtime.h>

#define TT   512
#define BB   4
#define OUTL 261632        // per-batch trimmed output length

// LDS swizzle (float4 units): uniform 8-lanes-per-bank-quad for every access
// pattern in this kernel (stage A/B/C/D reads+writes) -> optimal b128 service.
__device__ __forceinline__ int sw(int x) { return x ^ ((x >> 3) & 7); }

__device__ __forceinline__ float2 cmul(float2 a, float2 w) {
    return make_float2(a.x * w.x - a.y * w.y, a.x * w.y + a.y * w.x);
}

// inverse 8-point DFT (+i convention): o[k] = sum_l a[l] e^{+2pi i k l/8}
__device__ __forceinline__ void dft8(const float2 a[8], float2 o[8]) {
    float e0r = a[0].x + a[4].x, e0i = a[0].y + a[4].y;
    float e1r = a[0].x - a[4].x, e1i = a[0].y - a[4].y;
    float e2r = a[2].x + a[6].x, e2i = a[2].y + a[6].y;
    float e3r = a[6].y - a[2].y, e3i = a[2].x - a[6].x;   // i*(a2-a6)
    float E0r = e0r + e2r, E0i = e0i + e2i;
    float E1r = e1r + e3r, E1i = e1i + e3i;
    float E2r = e0r - e2r, E2i = e0i - e2i;
    float E3r = e1r - e3r, E3i = e1i - e3i;
    float f0r = a[1].x + a[5].x, f0i = a[1].y + a[5].y;
    float f1r = a[1].x - a[5].x, f1i = a[1].y - a[5].y;
    float f2r = a[3].x + a[7].x, f2i = a[3].y + a[7].y;
    float f3r = a[7].y - a[3].y, f3i = a[3].x - a[7].x;   // i*(a3-a7)
    float O0r = f0r + f2r, O0i = f0i + f2i;
    float O1r = f1r + f3r, O1i = f1i + f3i;
    float O2r = f0r - f2r, O2i = f0i - f2i;
    float O3r = f1r - f3r, O3i = f1i - f3i;
    const float h = 0.70710678118654752f;
    float W1r = h * (O1r - O1i), W1i = h * (O1r + O1i);   // w^1 * O1
    float W2r = -O2i,            W2i = O2r;               // i * O2
    float W3r = -h * (O3r + O3i), W3i = h * (O3r - O3i);  // w^3 * O3
    o[0] = make_float2(E0r + O0r, E0i + O0i);
    o[1] = make_float2(E1r + W1r, E1i + W1i);
    o[2] = make_float2(E2r + W2r, E2i + W2i);
    o[3] = make_float2(E3r + W3r, E3i + W3i);
    o[4] = make_float2(E0r - O0r, E0i - O0i);
    o[5] = make_float2(E1r - W1r, E1i - W1i);
    o[6] = make_float2(E2r - W2r, E2i - W2i);
    o[7] = make_float2(E3r - W3r, E3i - W3i);
}

// o[k] *= w1^k
__device__ __forceinline__ void twpow8(float2 o[8], float2 w1) {
    float2 w2 = cmul(w1, w1);
    float2 w3 = cmul(w2, w1);
    float2 w4 = cmul(w2, w2);
    o[1] = cmul(o[1], w1);
    o[2] = cmul(o[2], w2);
    o[3] = cmul(o[3], w3);
    o[4] = cmul(o[4], w4);
    o[5] = cmul(o[5], cmul(w4, w1));
    o[6] = cmul(o[6], cmul(w4, w2));
    o[7] = cmul(o[7], cmul(w4, w3));
}

// one butterfly: unpack float4 pair, dft8 both cols, twiddle, pack to tile
__device__ __forceinline__ void bfly8(const float4 a[8], float2 w1,
                                      float4* tile, int base8) {
    float2 x0[8], x1[8], o0[8], o1[8];
    #pragma unroll
    for (int l = 0; l < 8; l++) {
        x0[l] = make_float2(a[l].x, a[l].y);
        x1[l] = make_float2(a[l].z, a[l].w);
    }
    dft8(x0, o0); twpow8(o0, w1);
    dft8(x1, o1); twpow8(o1, w1);
    #pragma unroll
    for (int k = 0; k < 8; k++)
        tile[sw(base8 + k)] = make_float4(o0[k].x, o0[k].y, o1[k].x, o1[k].y);
}

// Fused iSTFT: one block = 2 consecutive t-columns, 128 threads, 32KB tile,
// 5 blocks/CU. Radix 8*8*8*4; stage A fused with global load; stage D writes
// windowed real frames; OLA via coalesced atomics.
__global__ __launch_bounds__(128) void istft_k(const float* __restrict__ X,
                                               const float* __restrict__ kc,
                                               const float* __restrict__ ks,
                                               const float* __restrict__ win,
                                               float* __restrict__ out) {
    __shared__ float4 tile[2048];          // exactly 32 KiB

    const int S  = blockIdx.x;
    // XCD remap: the 4 blocks sharing each 64B X-line are co-resident per XCD
    const int L  = ((S & 7) << 7) | (S >> 3);    // 0..1023
    const int c0 = L * 2;
    const int b  = c0 >> 9;
    const int t0 = c0 & 511;
    const int u  = threadIdx.x;                  // 0..127

    const float* twc = kc + 2048;   // cos(2*pi*m/2048) (kernel row n=1)
    const float* tws = ks + 2048;   // +sin (inverse transform)

    // per-thread twiddles (global, L1-cached)
    const int mB = 8 * (u >> 3), mC = 64 * (u >> 6);
    float2 wA0 = make_float2(twc[u], tws[u]);
    float2 wA1 = make_float2(twc[u + 128], tws[u + 128]);
    float2 wB0 = make_float2(twc[mB], tws[mB]);
    float2 wB1 = make_float2(twc[mB + 128], tws[mB + 128]);
    float2 wC0 = make_float2(twc[mC], tws[mC]);
    float2 wC1 = make_float2(twc[mC + 128], tws[mC + 128]);

    // ---- stage A (radix-8, s=1) fused with global load; 2 butterflies ----
    const float* Xb = X + ((size_t)b * 2048 * 512 + t0) * 2;
    float4 a0[8], a1[8];
    #pragma unroll
    for (int l = 0; l < 8; l++) {
        a0[l] = *reinterpret_cast<const float4*>(Xb + (size_t)(u + 256 * l) * 1024);
        a1[l] = *reinterpret_cast<const float4*>(Xb + (size_t)(u + 128 + 256 * l) * 1024);
    }
    bfly8(a0, wA0, tile, 8 * u);
    bfly8(a1, wA1, tile, 8 * (u + 128));
    __syncthreads();

    // ---- stage B (radix-8, s=8) ----
    #pragma unroll
    for (int l = 0; l < 8; l++) {
        a0[l] = tile[sw(u + 256 * l)];
        a1[l] = tile[sw(u + 128 + 256 * l)];
    }
    __syncthreads();
    {
        int b0 = 64 * (u >> 3) + (u & 7);
        // scatter dst = base + 8k: pass through bfly with manual store
        float2 x0[8], x1[8], o0[8], o1[8];
        #pragma unroll
        for (int l = 0; l < 8; l++) { x0[l] = make_float2(a0[l].x, a0[l].y); x1[l] = make_float2(a0[l].z, a0[l].w); }
        dft8(x0, o0); twpow8(o0, wB0);
        dft8(x1, o1); twpow8(o1, wB0);
        #pragma unroll
        for (int k = 0; k < 8; k++)
            tile[sw(b0 + 8 * k)] = make_float4(o0[k].x, o0[k].y, o1[k].x, o1[k].y);
        #pragma unroll
        for (int l = 0; l < 8; l++) { x0[l] = make_float2(a1[l].x, a1[l].y); x1[l] = make_float2(a1[l].z, a1[l].w); }
        dft8(x0, o0); twpow8(o0, wB1);
        dft8(x1, o1); twpow8(o1, wB1);
        #pragma unroll
        for (int k = 0; k < 8; k++)
            tile[sw(b0 + 1024 + 8 * k)] = make_float4(o0[k].x, o0[k].y, o1[k].x, o1[k].y);
    }
    __syncthreads();

    // ---- stage C (radix-8, s=64) ----
    #pragma unroll
    for (int l = 0; l < 8; l++) {
        a0[l] = tile[sw(u + 256 * l)];
        a1[l] = tile[sw(u + 128 + 256 * l)];
    }
    __syncthreads();
    {
        int b0 = 512 * (u >> 6) + (u & 63);
        float2 x0[8], x1[8], o0[8], o1[8];
        #pragma unroll
        for (int l = 0; l < 8; l++) { x0[l] = make_float2(a0[l].x, a0[l].y); x1[l] = make_float2(a0[l].z, a0[l].w); }
        dft8(x0, o0); twpow8(o0, wC0);
        dft8(x1, o1); twpow8(o1, wC0);
        #pragma unroll
        for (int k = 0; k < 8; k++)
            tile[sw(b0 + 64 * k)] = make_float4(o0[k].x, o0[k].y, o1[k].x, o1[k].y);
        #pragma unroll
        for (int l = 0; l < 8; l++) { x0[l] = make_float2(a1[l].x, a1[l].y); x1[l] = make_float2(a1[l].z, a1[l].w); }
        dft8(x0, o0); twpow8(o0, wC1);
        dft8(x1, o1); twpow8(o1, wC1);
        #pragma unroll
        for (int k = 0; k < 8; k++)
            tile[sw(b0 + 1024 + 64 * k)] = make_float4(o0[k].x, o0[k].y, o1[k].x, o1[k].y);
    }
    __syncthreads();

    // ---- stage D (radix-4, s=512, no twiddle): 4 butterflies/thread,
    //      real parts only, windowed, written as float2 frames fD[0..2048) ----
    float4 d[4][4];
    #pragma unroll
    for (int bi = 0; bi < 4; bi++) {
        int j = u + 128 * bi;
        #pragma unroll
        for (int m = 0; m < 4; m++) d[bi][m] = tile[sw(j + 512 * m)];
    }
    __syncthreads();
    float2* fD = (float2*)tile;
    #pragma unroll
    for (int bi = 0; bi < 4; bi++) {
        int j = u + 128 * bi;
        float4 d0 = d[bi][0], d1 = d[bi][1], d2 = d[bi][2], d3 = d[bi][3];
        float p0 = d0.x + d2.x, p1 = d0.x - d2.x;
        float p2 = d1.x + d3.x, p3 = d3.y - d1.y;
        float q0 = d0.z + d2.z, q1 = d0.z - d2.z;
        float q2 = d1.z + d3.z, q3 = d3.w - d1.w;
        float w0 = win[j], w1 = win[j + 512], w2 = win[j + 1024], w3 = win[j + 1536];
        fD[j]        = make_float2((p0 + p2) * w0, (q0 + q2) * w0);
        fD[j + 512]  = make_float2((p1 + p3) * w1, (q1 + q3) * w1);
        fD[j + 1024] = make_float2((p0 - p2) * w2, (q0 - q2) * w2);
        fD[j + 1536] = make_float2((p1 - p3) * w3, (q1 - q3) * w3);
    }
    __syncthreads();

    // ---- OLA + normalization over untrimmed [t0*512, t0*512+2560) ----
    const bool interior = (t0 >= 3) && (t0 <= 507);
    float invw[4];
    if (interior) {
        #pragma unroll
        for (int i = 0; i < 4; i++) {
            int rr = u + 128 * i;                  // < 512
            float s = 0.f;
            #pragma unroll
            for (int k = 0; k < 4; k++) { float w = win[rr + 512 * k]; s += w * w; }
            invw[i] = 1.0f / (2048.0f * s);
        }
    }
    float* outb = out + (size_t)b * OUTL;
    #pragma unroll 1
    for (int q = 0; q < 20; q++) {
        int jl = u + 128 * q;                      // 0..2559
        float contrib = 0.f;
        if (jl < 2048) contrib += fD[jl].x;        // frame t0
        if (jl >= 512) contrib += fD[jl - 512].y;  // frame t0+1
        int j  = t0 * 512 + jl;
        int jp = j - 1024;
        if (jp < 0 || jp >= OUTL) continue;
        float y;
        if (interior) {
            y = contrib * invw[q & 3];
        } else {
            int tb = j >> 9, r = j & 511;
            float s = 0.f;
            #pragma unroll
            for (int k = 0; k < 4; k++) {
                int t = tb - k;
                if (t >= 0 && t < TT) { float w = win[r + (k << 9)]; s += w * w; }
            }
            y = contrib * (1.0f / 2048.0f);
            if (s > 1e-10f) y /= s;
        }
        atomicAdd(outb + jp, y);
    }
}

extern "C" void kernel_launch(void* const* d_in, const int* in_sizes, int n_in,
                              void* d_out, int out_size, void* d_ws, size_t ws_size,
                              hipStream_t stream) {
    const float* X  = (const float*)d_in[0];
    const float* kc = (const float*)d_in[1];
    const float* ks = (const float*)d_in[2];
    const float* w  = (const float*)d_in[3];
    float* out = (float*)d_out;

    hipMemsetAsync(out, 0, (size_t)out_size * sizeof(float), stream);
    istft_k<<<dim3(BB * TT / 2), dim3(128), 0, stream>>>(X, kc, ks, w, out);
}

// Round 10
// 37.886 us; speedup vs baseline: 1.0752x; 1.0752x over previous
//
#include <hip/hip_runtime.h>

#define TT   512
#define BB   4
#define OUTL 261632        // per-batch trimmed output length

// padded float2 slot in the per-column Z buffer (breaks stride-4 bank camping)
#define ZP(k) ((k) + ((k) >> 3))

__device__ __forceinline__ float2 cmul(float2 a, float2 w) {
    return make_float2(a.x * w.x - a.y * w.y, a.x * w.y + a.y * w.x);
}

// radix-4 DIT butterfly (inverse, +i), twiddles w1, w1^2, w1^3 (r3-proven)
__device__ __forceinline__ void bf4(const float2 a[4], float2 o[4], float2 w1) {
    float2 w2 = make_float2(w1.x * w1.x - w1.y * w1.y, 2.f * w1.x * w1.y);
    float2 w3 = cmul(w1, w2);
    float t0r = a[0].x + a[2].x, t0i = a[0].y + a[2].y;
    float t1r = a[0].x - a[2].x, t1i = a[0].y - a[2].y;
    float t2r = a[1].x + a[3].x, t2i = a[1].y + a[3].y;
    float t3r = a[3].y - a[1].y, t3i = a[1].x - a[3].x;   // i*(a1-a3)
    o[0] = make_float2(t0r + t2r, t0i + t2i);
    o[1] = cmul(make_float2(t1r + t3r, t1i + t3i), w1);
    o[2] = cmul(make_float2(t0r - t2r, t0i - t2i), w2);
    o[3] = cmul(make_float2(t1r - t3r, t1i - t3i), w3);
}

// ---- tr_k: X[b][f][t][2] -> Xt[(b*512+t)][f] (float2), 64x64 LDS tiles ----
__global__ __launch_bounds__(256) void tr_k(const float* __restrict__ X,
                                            float* __restrict__ Xt) {
    __shared__ float2 tile[64][65];
    const int f0 = blockIdx.x * 64;
    const int t0 = blockIdx.y * 64;
    const int b  = blockIdx.z;
    const int tid = threadIdx.x;
    #pragma unroll
    for (int it = 0; it < 8; it++) {
        int idx = it * 256 + tid;          // 0..2047
        int fi = idx >> 5;                 // 0..63
        int tj = (idx & 31) * 2;           // 0..62
        const float4 v = *reinterpret_cast<const float4*>(
            X + (((size_t)(b * 2048 + f0 + fi)) * 512 + t0 + tj) * 2);
        tile[fi][tj]     = make_float2(v.x, v.y);
        tile[fi][tj + 1] = make_float2(v.z, v.w);
    }
    __syncthreads();
    #pragma unroll
    for (int it = 0; it < 8; it++) {
        int idx = it * 256 + tid;
        int ti = idx >> 5;
        int fj = (idx & 31) * 2;
        int c  = b * 512 + t0 + ti;
        float2 p = tile[fj][ti];
        float2 q = tile[fj + 1][ti];
        *reinterpret_cast<float4*>(Xt + ((size_t)c * 2048 + f0 + fj) * 2) =
            make_float4(p.x, p.y, q.x, q.y);
    }
}

// mid stage of the 1024-pt radix-4 Stockham (stride SS), on padded Z buffer
template<int SS>
__device__ __forceinline__ void mid1024(float2* Zg, int u,
                                        const float* twc, const float* tws) {
    float2 a[4], o[4];
    #pragma unroll
    for (int q = 0; q < 4; q++) a[q] = Zg[ZP(u + 256 * q)];
    __syncthreads();
    const int mA = u & ~(SS - 1), rA = u & (SS - 1);
    bf4(a, o, make_float2(twc[2 * mA], tws[2 * mA]));   // W_1024^mA
    const int j = 4 * mA + rA;
    #pragma unroll
    for (int k = 0; k < 4; k++) Zg[ZP(j + SS * k)] = o[k];
    __syncthreads();
}

// ---- fused iSTFT: one block = 2 columns; per column a 1024-pt packed
//      real-output inverse FFT (conjugate pack), window, OLA via atomics ----
__global__ __launch_bounds__(512, 6) void istft_k(const float* __restrict__ Xt,
                                                  const float* __restrict__ kc,
                                                  const float* __restrict__ ks,
                                                  const float* __restrict__ win,
                                                  float* __restrict__ out) {
    __shared__ float2 Z[2][1152];          // 2 x 9.2KB (padded); reused as frames

    const int S = blockIdx.x;
    const int L = ((S & 7) << 7) | (S >> 3);   // XCD swizzle (1024 blocks)
    const int c0 = L * 2;
    const int b  = c0 >> 9;
    const int t0 = c0 & 511;               // even
    const int tid = threadIdx.x;
    const int g = tid >> 8;                // column in block
    const int u = tid & 255;
    const float2* Xc = reinterpret_cast<const float2*>(Xt) + (size_t)(c0 + g) * 2048;
    const float* twc = kc + 2048;          // cos(2*pi*m/2048) (kernel row n=1)
    const float* tws = ks + 2048;          // +sin (inverse)
    float2* Zg = Z[g];

    // ---- pack (X -> Z) fused with stage A (s=1) ----
    float2 a[4], o[4];
    #pragma unroll
    for (int l = 0; l < 4; l++) {
        int k = u + 256 * l;               // 0..1023
        float2 Xk  = Xc[k];
        float2 Xrv = Xc[(2048 - k) & 2047];
        float2 Xk1 = Xc[1024 + k];
        float2 Xm1 = Xc[1024 - k];
        float2 Yk  = make_float2(0.5f * (Xk.x + Xrv.x),  0.5f * (Xk.y - Xrv.y));
        float2 Yk1 = make_float2(0.5f * (Xk1.x + Xm1.x), 0.5f * (Xk1.y - Xm1.y));
        float2 A = make_float2(Yk.x + Yk1.x, Yk.y + Yk1.y);
        float2 D = make_float2(Yk.x - Yk1.x, Yk.y - Yk1.y);
        float2 Bv = cmul(D, make_float2(twc[k], tws[k]));   // e^{2pi i k/2048}
        a[l] = make_float2(A.x - Bv.y, A.y + Bv.x);         // Z[k] = A + iB
    }
    bf4(a, o, make_float2(twc[2 * u], tws[2 * u]));         // W_1024^u
    #pragma unroll
    for (int k = 0; k < 4; k++) Zg[ZP(4 * u + k)] = o[k];
    __syncthreads();

    // ---- stages s=4,16,64 ----
    mid1024<4>(Zg, u, twc, tws);
    mid1024<16>(Zg, u, twc, tws);
    mid1024<64>(Zg, u, twc, tws);

    // ---- stage s=256 (no twiddle) + reconstruct + window -> frames ----
    float2 e[4], z[4];
    #pragma unroll
    for (int q = 0; q < 4; q++) e[q] = Zg[ZP(u + 256 * q)];
    __syncthreads();
    bf4(e, z, make_float2(1.f, 0.f));
    float* fr = reinterpret_cast<float*>(Zg);
    #pragma unroll
    for (int k = 0; k < 4; k++) {
        int m = u + 256 * k;               // z[m]: x[2m]=Re, x[2m+1]=Im
        fr[2 * m]     = z[k].x * win[2 * m];
        fr[2 * m + 1] = z[k].y * win[2 * m + 1];
    }
    __syncthreads();

    // ---- OLA + normalization over untrimmed [t0*512, t0*512+2560) ----
    const float* frA = reinterpret_cast<const float*>(Z[0]);   // frame t0
    const float* frB = reinterpret_cast<const float*>(Z[1]);   // frame t0+1
    const bool interior = (t0 >= 3) && (t0 <= 507);
    float invw;
    {
        int rr = tid & 511;
        float s = 0.f;
        #pragma unroll
        for (int kk = 0; kk < 4; kk++) { float w = win[rr + 512 * kk]; s += w * w; }
        invw = 1.0f / (2048.0f * s);       // s >= 1.5 always
    }
    float* outb = out + (size_t)b * OUTL;
    #pragma unroll
    for (int q = 0; q < 5; q++) {
        int jl = tid + 512 * q;            // 0..2559
        float contrib = 0.f;
        if (jl < 2048) contrib += frA[jl];
        int j2 = jl - 512;
        if (j2 >= 0 && j2 < 2048) contrib += frB[j2];
        int j  = t0 * 512 + jl;
        int jp = j - 1024;
        if (jp < 0 || jp >= OUTL) continue;
        float y;
        if (interior) {
            y = contrib * invw;
        } else {
            int tb = j >> 9, rr = j & 511;
            float s = 0.f;
            #pragma unroll
            for (int kk = 0; kk < 4; kk++) {
                int t = tb - kk;
                if (t >= 0 && t < TT) { float w = win[rr + (kk << 9)]; s += w * w; }
            }
            y = contrib * (1.0f / 2048.0f);
            if (s > 1e-10f) y /= s;
        }
        atomicAdd(outb + jp, y);
    }
}

extern "C" void kernel_launch(void* const* d_in, const int* in_sizes, int n_in,
                              void* d_out, int out_size, void* d_ws, size_t ws_size,
                              hipStream_t stream) {
    const float* X  = (const float*)d_in[0];
    const float* kc = (const float*)d_in[1];
    const float* ks = (const float*)d_in[2];
    const float* w  = (const float*)d_in[3];
    float* out = (float*)d_out;
    float* Xt  = (float*)d_ws;                 // 2048*2048 float2 = 33.6 MB

    hipMemsetAsync(out, 0, (size_t)out_size * sizeof(float), stream);
    tr_k<<<dim3(32, 8, 4), dim3(256), 0, stream>>>(X, Xt);
    istft_k<<<dim3(BB * TT / 2), dim3(512), 0, stream>>>(Xt, kc, ks, w, out);
}